// Round 3
// baseline (874.444 us; speedup 1.0000x reference)
//
#include <hip/hip_runtime.h>
#include <stdint.h>

// CTC forward loss, B=512, T=1024, C=256, L=64, S=129, blank=C-1.
//
// R3: two-kernel split.
//  K1 (gather, massively parallel): for each (b,t) stage the 1KB prob row
//     through LDS (coalesced float4 global reads), gather the 64 label
//     entries + blank, store log(p+EPS) to workspace:
//       G[b][t][64]  (per-lane label log-probs, coalesced for K2)
//       Bk[b][t]     (blank log-prob)
//     Latency hidden by occupancy (131072 blocks), both global streams
//     fully coalesced.
//  K2 (scan, 1 wave/batch): per step one coalesced 4B/lane load + one
//     uniform load; depth-16 register ring; compiler-tracked vmcnt (loads
//     return to VGPRs -> no conservative vmcnt(0) drain, unlike the R2
//     global_load_lds ring). No LDS, no barriers.

#define EPS 1e-7f
#define NEG -1e30f

constexpr int Bb = 512;
constexpr int Tt = 1024;
constexpr int Cc = 256;
constexpr int Ll = 64;
constexpr int BLANK = Cc - 1;
constexpr int DPF = 16;

// ---------------- K1: gather + log ----------------
// grid = Bb * (Tt/4) blocks, 256 threads. Block handles one b, 4 consecutive t.
__global__ __launch_bounds__(256) void ctc_gather_kernel(
    const int* __restrict__ y_true,   // [B,L]
    const float* __restrict__ y_pred, // [B,T,C]
    float* __restrict__ G,            // [B,T,64]
    float* __restrict__ Bk)           // [B,T]
{
    const int blk = blockIdx.x;
    const int b = blk >> 8;   // / (Tt/4)
    const int tg = blk & 255; // t-group
    const int t0 = tg * 4;
    const int tid = threadIdx.x;
    const int w = tid >> 6;   // wave -> which of the 4 rows
    const int lane = tid & 63;

    __shared__ float rows[4 * Cc]; // 4 KiB

    // coalesced stage: 256 threads x 16B = 4KB (4 rows)
    const float4* __restrict__ src =
        (const float4*)(y_pred + ((size_t)b * Tt + t0) * Cc);
    ((float4*)rows)[tid] = src[tid];

    const int lab = y_true[b * Ll + lane];
    __syncthreads();

    const int t = t0 + w;
    // random-label LDS gather: ~2-way bank conflict avg (free on gfx950)
    const float v = __logf(rows[w * Cc + lab] + EPS);
    G[((size_t)b * Tt + t) * 64 + lane] = v; // coalesced 256B store per wave
    if (lane == 0)
        Bk[b * Tt + t] = __logf(rows[w * Cc + BLANK] + EPS);
}

// ---------------- K2: the alpha scan ----------------
__global__ __launch_bounds__(64) void ctc_scan_kernel(
    const int* __restrict__ y_true, // [B,L]
    const float* __restrict__ G,    // [B,T,64] log p(label_lane) at (b,t)
    const float* __restrict__ Bk,   // [B,T]    log p(blank) at (b,t)
    float* __restrict__ out)        // [B]
{
    const int b = blockIdx.x;
    const int lane = threadIdx.x;

    const float* __restrict__ g = G + (size_t)b * Tt * 64;
    const float* __restrict__ bk = Bk + (size_t)b * Tt;

    const int lab = y_true[b * Ll + lane];
    const int lab_prev = __shfl_up(lab, 1);
    const bool allow = (lane == 0) ? true : (lab != lab_prev);

    // t = 0 init (only lane 0's states live)
    const float g0 = g[lane]; // lane0 -> log p(label_0)
    const float b0 = bk[0];
    float ae = (lane == 0) ? b0 : NEG; // alpha[2i]
    float ao = (lane == 0) ? g0 : NEG; // alpha[2i+1]
    float a128 = NEG;                  // alpha[128] (lane 63)

    // register ring prefetch, depth 16
    float pl[DPF], pb[DPF];
#pragma unroll
    for (int j = 0; j < DPF; ++j) {
        const int t = 1 + j;
        pl[j] = g[(size_t)t * 64 + lane]; // coalesced dword
        pb[j] = bk[t];                    // uniform (scalarizes)
    }

    int t = 1;

    auto step = [&](int slot, bool do_prefetch) {
        const float lpl = pl[slot];
        const float lpb = pb[slot];
        if (do_prefetch) {
            const int tn = t + DPF;
            if (tn < Tt) {
                pl[slot] = g[(size_t)tn * 64 + lane];
                pb[slot] = bk[tn];
            }
        }
        float ao_up = __shfl_up(ao, 1);
        if (lane == 0) ao_up = NEG;

        // even state s=2i: from alpha[2i], alpha[2i-1]; emits blank
        const float m2 = fmaxf(ae, ao_up);
        const float ne =
            m2 + __logf(__expf(ae - m2) + __expf(ao_up - m2)) + lpb;

        // odd state s=2i+1: from alpha[2i+1], alpha[2i], (allow) alpha[2i-1]
        const float a3 = allow ? ao_up : NEG;
        const float m3 = fmaxf(fmaxf(ao, ae), a3);
        const float no =
            m3 +
            __logf(__expf(ao - m3) + __expf(ae - m3) + __expf(a3 - m3)) +
            lpl;

        // state 128 (lane 63): from alpha[128], alpha[127]; emits blank
        const float m1 = fmaxf(a128, ao);
        const float n128 =
            m1 + __logf(__expf(a128 - m1) + __expf(ao - m1)) + lpb;

        ae = ne;
        ao = no;
        a128 = n128;
        ++t;
    };

    // main: 63 chunks x 16 steps (t = 1 .. 1008)
    for (int chunk = 0; chunk < (Tt - 1) / DPF; ++chunk) {
#pragma unroll
        for (int k = 0; k < DPF; ++k) step(k, true);
    }
    // remainder: 15 steps (t = 1009 .. 1023)
#pragma unroll
    for (int k = 0; k < (Tt - 1) % DPF; ++k) step(k, false);

    if (lane == 63) {
        const float m = fmaxf(a128, ao);
        out[b] = -(m + __logf(__expf(a128 - m) + __expf(ao - m)));
    }
}

extern "C" void kernel_launch(void* const* d_in, const int* in_sizes, int n_in,
                              void* d_out, int out_size, void* d_ws,
                              size_t ws_size, hipStream_t stream) {
    const int* y_true = (const int*)d_in[0];     // [512,64] int32
    const float* y_pred = (const float*)d_in[1]; // [512,1024,256] fp32
    float* out = (float*)d_out;                  // [512] fp32

    // workspace carve: G = 512*1024*64 floats (128 MiB), Bk = 512*1024 (2 MiB)
    float* G = (float*)d_ws;
    float* Bk = (float*)((char*)d_ws + (size_t)Bb * Tt * 64 * sizeof(float));

    ctc_gather_kernel<<<dim3(Bb * (Tt / 4)), dim3(256), 0, stream>>>(
        y_true, y_pred, G, Bk);
    ctc_scan_kernel<<<dim3(Bb), dim3(64), 0, stream>>>(y_true, G, Bk, out);
}